// Round 3
// baseline (457.549 us; speedup 1.0000x reference)
//
#include <hip/hip_runtime.h>
#include <math.h>

typedef __attribute__((ext_vector_type(4))) float f32x4;
typedef __attribute__((ext_vector_type(8))) short s16x8;
typedef __attribute__((ext_vector_type(8))) unsigned short u16x8;
typedef __attribute__((ext_vector_type(4))) unsigned short u16x4;

#define NB 32
#define NN 1000
#define NT 24
#define NP 1024
#define TCN 768

#define GLOAD16(g, l) __builtin_amdgcn_global_load_lds( \
    (const __attribute__((address_space(1))) unsigned int*)(g), \
    (__attribute__((address_space(3))) unsigned int*)(l), 16, 0, 0)

__device__ __forceinline__ unsigned short f2bf(float f){
  union { float fv; unsigned int u; } v; v.fv = f;
  unsigned int r = v.u + 0x7FFFu + ((v.u >> 16) & 1u);
  return (unsigned short)(r >> 16);
}

// ---------------- K0a: cheb[3][1000][1000] f32 -> cbT[3][1024][1024] bf16 (zero pad) ----
__global__ void k0_cheb(const float* __restrict__ cheb, unsigned short* __restrict__ cbT){
  int idx = blockIdx.x * 256 + threadIdx.x;      // 3*1024*1024/4 threads
  int base = idx << 2;
  int m = base & (NP - 1);
  int r = base >> 10;
  int n = r & (NP - 1);
  int k = r >> 10;
  u16x4 o;
  #pragma unroll
  for (int i = 0; i < 4; ++i){
    int mm = m + i;
    float v = (n < NN && mm < NN) ? cheb[((long)k*NN + n)*NN + mm] : 0.f;
    o[i] = f2bf(v);
  }
  *(u16x4*)(cbT + base) = o;
}

// ---------------- K0b: x -> xbT[b][t*32+c][1024 m] bf16 ; xt2[b][m][t*32+c] bf16 --------
__global__ __launch_bounds__(256) void k0_x(const float* __restrict__ x,
                     unsigned short* __restrict__ xbT, unsigned short* __restrict__ xt2){
  __shared__ unsigned short tile[64*770];        // pad 770: transpose reads conflict-free
  const int b  = blockIdx.x >> 4;
  const int m0 = (blockIdx.x & 15) << 6;
  const int tid = threadIdx.x;
  for (int i = tid; i < 64*192; i += 256){
    int mi = i / 192, c4 = (i - mi*192) << 2;
    f32x4 v = (f32x4){0.f,0.f,0.f,0.f};
    if (m0 + mi < NN) v = *(const f32x4*)(x + (size_t)(b*NN + m0 + mi)*768 + c4);
    unsigned short* tp = tile + mi*770 + c4;
    tp[0] = f2bf(v[0]); tp[1] = f2bf(v[1]); tp[2] = f2bf(v[2]); tp[3] = f2bf(v[3]);
  }
  __syncthreads();
  {
    const int seg = tid & 7, r0 = tid >> 3;
    for (int rr = 0; rr < 768; rr += 32){
      int r = rr + r0;
      int t = r >> 5, c = r & 31, ct = c*24 + t;
      u16x8 v;
      #pragma unroll
      for (int e = 0; e < 8; ++e) v[e] = tile[(seg*8 + e)*770 + ct];
      *(u16x8*)(xbT + ((size_t)b*TCN + r)*NP + m0 + seg*8) = v;
    }
  }
  if (m0 < NN){
    int rows = NN - m0; if (rows > 64) rows = 64;
    for (int i = tid; i < rows*96; i += 256){
      int mi = i / 96, s = i - mi*96;
      u16x8 v;
      #pragma unroll
      for (int e = 0; e < 8; ++e){
        int r = s*8 + e; int t = r >> 5, c = r & 31;
        v[e] = tile[mi*770 + c*24 + t];
      }
      *(u16x8*)(xt2 + (size_t)(b*NN + m0 + mi)*TCN + s*8) = v;
    }
  }
}

// ---------------- K0c: weights -> f-major bf16 ------------------------------------------
__global__ void k0_w(const float* __restrict__ Theta, const float* __restrict__ tw,
                     const float* __restrict__ rw,
                     unsigned short* __restrict__ ThT, unsigned short* __restrict__ WtT,
                     unsigned short* __restrict__ rwT){
  int i = blockIdx.x * 256 + threadIdx.x;
  if (i < 64*96){                       // ThT[f][kc] = Theta[k][c][f]
    int f = i / 96, kc = i - f*96;
    ThT[i] = f2bf(Theta[kc*64 + f]);
  }
  if (i < 64*192){                      // WtT[f][dt*64+fi] = tw[f][fi][0][dt]
    int f = i / 192, kk = i - f*192;
    int dt = kk >> 6, fi = kk & 63;
    WtT[i] = f2bf(tw[(f*64 + fi)*3 + dt]);
  }
  if (i < 64*32){                       // rwT[f][c] = rw[f][c][0][0]
    rwT[i] = f2bf(rw[i]);
  }
}

// ---------------- K1: fused cheb-GEMM (3k) + Theta-GEMM + relu -> spatial ----------------
// 512 threads / 8 waves (4 wr x 2 wc), block tile 128n x 64tc x 3k, BK=32,
// global_load_lds + both-sides XOR swizzle; 28KB LDS -> 2 blocks/CU, 4 waves/SIMD.
__global__ __launch_bounds__(512, 4) void k1_cheb_theta(
    const unsigned short* __restrict__ cbT,
    const unsigned short* __restrict__ xbT,
    const unsigned short* __restrict__ ThT,
    unsigned short* __restrict__ spa)
{
  __shared__ __align__(16) unsigned short smem[14336];  // 28.7KB: A[3][128][32]+B[64][32] / yl[128][104]

  int pB = blockIdx.x;
  int lb = (pB & 7) * 384 + (pB >> 3);     // bijective XCD-chunked swizzle (3072 = 8*384)
  const int tct = lb % 12; lb /= 12;       // 12 consecutive blocks share the A-panel
  const int nt  = lb & 7;
  const int b   = lb >> 3;

  const int tid  = threadIdx.x;
  const int wid  = tid >> 6;
  const int lane = tid & 63;
  const int l16  = lane & 15;
  const int k8   = lane >> 4;
  const int wr   = wid & 3;     // 32 n-rows each
  const int wc   = wid >> 2;    // 32 tc-cols each

  // staging: wave covers 16 rows x 4 chunks(16B); source chunk XOR-swizzled, LDS linear
  const int rl4  = lane >> 2;
  const int swz8 = (((lane & 3) ^ ((rl4 >> 1) & 3)) << 3);
  const unsigned short* gA = cbT + (size_t)(nt*128 + rl4)*NP + swz8;
  const unsigned short* gB = xbT + ((size_t)b*TCN + tct*64 + rl4)*NP + swz8;

  // read-side swizzled chunk offset (elems): depends only on lane
  const int rdsw = ((k8 ^ ((l16 >> 1) & 3)) << 3);

  f32x4 acc[3][2][2];
  #pragma unroll
  for (int k = 0; k < 3; ++k)
    #pragma unroll
    for (int i = 0; i < 2; ++i)
      #pragma unroll
      for (int j = 0; j < 2; ++j) acc[k][i][j] = (f32x4){0.f, 0.f, 0.f, 0.f};

  for (int step = 0; step < 32; ++step){
    __syncthreads();                         // previous step's reads done
    const int so = step << 5;
    #pragma unroll
    for (int q = 0; q < 4; ++q){
      const int g = wid + (q << 3);          // 28 1KB loads: 24 A + 4 B
      if (g < 24){
        const int k = g >> 3, rg = g & 7;
        GLOAD16(gA + (size_t)k*NP*NP + (size_t)rg*16*NP + so,
                (char*)smem + k*8192 + rg*1024);
      } else if (g < 28){
        const int rg = g - 24;
        GLOAD16(gB + (size_t)rg*16*NP + so,
                (char*)smem + 24576 + rg*1024);
      }
    }
    __syncthreads();                         // drains vmcnt -> data visible
    s16x8 af[3][2], bf[2];
    #pragma unroll
    for (int k = 0; k < 3; ++k)
      #pragma unroll
      for (int i = 0; i < 2; ++i)
        af[k][i] = *(const s16x8*)(smem + k*4096 + (wr*32 + i*16 + l16)*32 + rdsw);
    #pragma unroll
    for (int j = 0; j < 2; ++j)
      bf[j] = *(const s16x8*)(smem + 12288 + (wc*32 + j*16 + l16)*32 + rdsw);
    #pragma unroll
    for (int k = 0; k < 3; ++k)
      #pragma unroll
      for (int i = 0; i < 2; ++i)
        #pragma unroll
        for (int j = 0; j < 2; ++j)
          acc[k][i][j] = __builtin_amdgcn_mfma_f32_16x16x32_bf16(af[k][i], bf[j], acc[k][i][j], 0, 0, 0);
  }

  // ---- epilogue: two t-phases; y -> LDS bf16 -> Theta MFMA -> relu -> spa ----
  s16x8 b2[3][4];
  #pragma unroll
  for (int ch = 0; ch < 3; ++ch)
    #pragma unroll
    for (int j = 0; j < 4; ++j)
      b2[ch][j] = *(const s16x8*)(ThT + (j*16 + l16)*96 + ch*32 + k8*8);

  unsigned short* yl = smem;                 // [128 n][104 kc] per phase
  #pragma unroll
  for (int p = 0; p < 2; ++p){
    __syncthreads();                         // prior smem readers done
    if (wc == p){                            // this wave's acc belongs to t = tct*2 + p
      #pragma unroll
      for (int k = 0; k < 3; ++k)
        #pragma unroll
        for (int i = 0; i < 2; ++i)
          #pragma unroll
          for (int j = 0; j < 2; ++j){
            const int nb = wr*32 + i*16 + (k8 << 2);
            #pragma unroll
            for (int r = 0; r < 4; ++r)
              yl[(nb + r)*104 + k*32 + j*16 + l16] = f2bf(acc[k][i][j][r]);
          }
    }
    __syncthreads();
    f32x4 acc2[4];
    #pragma unroll
    for (int j = 0; j < 4; ++j) acc2[j] = (f32x4){0.f,0.f,0.f,0.f};
    #pragma unroll
    for (int ch = 0; ch < 3; ++ch){
      s16x8 a2 = *(const s16x8*)(yl + (size_t)(wid*16 + l16)*104 + ch*32 + k8*8);
      #pragma unroll
      for (int j = 0; j < 4; ++j)
        acc2[j] = __builtin_amdgcn_mfma_f32_16x16x32_bf16(a2, b2[ch][j], acc2[j], 0, 0, 0);
    }
    const int tg = tct*2 + p;
    #pragma unroll
    for (int j = 0; j < 4; ++j)
      #pragma unroll
      for (int r = 0; r < 4; ++r){
        const int n = nt*128 + wid*16 + (k8 << 2) + r;
        if (n < NN)
          spa[((size_t)(b*NN + n)*NT + tg)*64 + j*16 + l16] = f2bf(fmaxf(acc2[j][r], 0.f));
      }
  }
}

// ---------------- K2: time-conv (K=192) + residual (K=32) + gating -> out f32 -----------
__global__ __launch_bounds__(256, 2) void k2_out(
    const unsigned short* __restrict__ spa, const unsigned short* __restrict__ xt2,
    const unsigned short* __restrict__ WtT, const unsigned short* __restrict__ rwT,
    const float* __restrict__ tb, const float* __restrict__ rb,
    float* __restrict__ out)
{
  const int tid  = threadIdx.x;
  const int wid  = tid >> 6;
  const int lane = tid & 63;
  const int l16  = lane & 15;
  const int k8   = lane >> 4;
  const int gwave = blockIdx.x * 4 + wid;     // 0..5999

  s16x8 bw[6][4], br[4];
  #pragma unroll
  for (int ch = 0; ch < 6; ++ch)
    #pragma unroll
    for (int j = 0; j < 4; ++j)
      bw[ch][j] = *(const s16x8*)(WtT + (j*16 + l16)*192 + ch*32 + k8*8);
  #pragma unroll
  for (int j = 0; j < 4; ++j)
    br[j] = *(const s16x8*)(rwT + (j*16 + l16)*32 + k8*8);
  float tbv[4], rbv[4];
  #pragma unroll
  for (int j = 0; j < 4; ++j){ tbv[j] = tb[j*16 + l16]; rbv[j] = rb[j*16 + l16]; }

  for (int it = 0; it < 8; ++it){
    const int r0 = (gwave*8 + it) * 16;       // base row, rows = (b*1000+n)*24+t
    const int rowA = r0 + l16;
    const int tA = rowA % 24;
    const int bn = rowA / 24;
    f32x4 acc_tc[4], acc_res[4];
    #pragma unroll
    for (int j = 0; j < 4; ++j){ acc_tc[j] = (f32x4){0.f,0.f,0.f,0.f}; acc_res[j] = (f32x4){0.f,0.f,0.f,0.f}; }

    #pragma unroll
    for (int ch = 0; ch < 6; ++ch){
      const int dt = ch >> 1, fh = (ch & 1) << 5;
      const int ts = tA + dt - 1;
      s16x8 a = (s16x8){0,0,0,0,0,0,0,0};
      if (ts >= 0 && ts < 24)
        a = *(const s16x8*)(spa + ((size_t)(bn*24 + ts) << 6) + fh + k8*8);
      #pragma unroll
      for (int j = 0; j < 4; ++j)
        acc_tc[j] = __builtin_amdgcn_mfma_f32_16x16x32_bf16(a, bw[ch][j], acc_tc[j], 0, 0, 0);
    }
    {
      s16x8 a = *(const s16x8*)(xt2 + (size_t)bn*768 + tA*32 + k8*8);
      #pragma unroll
      for (int j = 0; j < 4; ++j)
        acc_res[j] = __builtin_amdgcn_mfma_f32_16x16x32_bf16(a, br[j], acc_res[j], 0, 0, 0);
    }

    const int rowD = r0 + (k8 << 2);
    const int tD  = rowD % 24;                // multiple of 4, +3 never crosses 24
    const int bnD = rowD / 24;
    #pragma unroll
    for (int j = 0; j < 4; ++j){
      f32x4 v;
      #pragma unroll
      for (int r = 0; r < 4; ++r){
        float z = acc_tc[j][r] + tbv[j];
        float e = __expf(-z);                 // tanh(z)*sigmoid(z) = (1-e)/(1+e^2)
        float p = (1.f - e) * __builtin_amdgcn_rcpf(1.f + e*e);
        v[r] = acc_res[j][r] + rbv[j] + p;
      }
      *(f32x4*)(out + (((size_t)bnD << 6) + j*16 + l16)*24 + tD) = v;
    }
  }
}

// ---------------- launch -----------------------------------------------------------------
extern "C" void kernel_launch(void* const* d_in, const int* in_sizes, int n_in,
                              void* d_out, int out_size, void* d_ws, size_t ws_size,
                              hipStream_t stream) {
  const float* x     = (const float*)d_in[0];
  const float* cheb  = (const float*)d_in[1];
  const float* Theta = (const float*)d_in[2];
  const float* tw    = (const float*)d_in[3];
  const float* tb    = (const float*)d_in[4];
  const float* rw    = (const float*)d_in[5];
  const float* rb    = (const float*)d_in[6];
  float* out = (float*)d_out;

  char* ws = (char*)d_ws;
  size_t off = 0;
  auto alloc = [&](size_t bytes) -> void* {
    void* p = ws + off;
    off += (bytes + 255) & ~(size_t)255;
    return p;
  };
  unsigned short* cbT = (unsigned short*)alloc((size_t)3*NP*NP*2);        //  6.3 MB
  unsigned short* xbT = (unsigned short*)alloc((size_t)NB*TCN*NP*2);      // 50.3 MB
  unsigned short* xt2 = (unsigned short*)alloc((size_t)NB*NN*TCN*2);      // 49.2 MB
  unsigned short* spa = (unsigned short*)alloc((size_t)NB*NN*NT*64*2);    // 98.3 MB
  unsigned short* ThT = (unsigned short*)alloc((size_t)64*96*2);
  unsigned short* WtT = (unsigned short*)alloc((size_t)64*192*2);
  unsigned short* rwT = (unsigned short*)alloc((size_t)64*32*2);

  hipLaunchKernelGGL(k0_cheb, dim3(3072), dim3(256), 0, stream, cheb, cbT);
  hipLaunchKernelGGL(k0_x,    dim3(512),  dim3(256), 0, stream, x, xbT, xt2);
  hipLaunchKernelGGL(k0_w,    dim3(48),   dim3(256), 0, stream, Theta, tw, rw, ThT, WtT, rwT);
  hipLaunchKernelGGL(k1_cheb_theta, dim3(32*8*12), dim3(512), 0, stream, cbT, xbT, ThT, spa);
  hipLaunchKernelGGL(k2_out,  dim3(1500), dim3(256), 0, stream, spa, xt2, WtT, rwT, tb, rb, out);
}

// Round 4
// 443.578 us; speedup vs baseline: 1.0315x; 1.0315x over previous
//
#include <hip/hip_runtime.h>
#include <math.h>

typedef __attribute__((ext_vector_type(4))) float f32x4;
typedef __attribute__((ext_vector_type(16))) float f32x16;
typedef __attribute__((ext_vector_type(8))) short s16x8;
typedef __attribute__((ext_vector_type(8))) unsigned short u16x8;
typedef __attribute__((ext_vector_type(4))) unsigned short u16x4;

#define NB 32
#define NN 1000
#define NT 24
#define NP 1024
#define TCN 768

#define GLOAD16(g, l) __builtin_amdgcn_global_load_lds( \
    (const __attribute__((address_space(1))) unsigned int*)(g), \
    (__attribute__((address_space(3))) unsigned int*)(l), 16, 0, 0)

__device__ __forceinline__ unsigned short f2bf(float f){
  union { float fv; unsigned int u; } v; v.fv = f;
  unsigned int r = v.u + 0x7FFFu + ((v.u >> 16) & 1u);
  return (unsigned short)(r >> 16);
}

// ---------------- K0a: cheb[3][1000][1000] f32 -> cbT[3][1024][1024] bf16 (zero pad) ----
__global__ void k0_cheb(const float* __restrict__ cheb, unsigned short* __restrict__ cbT){
  int idx = blockIdx.x * 256 + threadIdx.x;      // 3*1024*1024/4 threads
  int base = idx << 2;
  int m = base & (NP - 1);
  int r = base >> 10;
  int n = r & (NP - 1);
  int k = r >> 10;
  u16x4 o;
  #pragma unroll
  for (int i = 0; i < 4; ++i){
    int mm = m + i;
    float v = (n < NN && mm < NN) ? cheb[((long)k*NN + n)*NN + mm] : 0.f;
    o[i] = f2bf(v);
  }
  *(u16x4*)(cbT + base) = o;
}

// ---------------- K0b: x -> xbT[b][t*32+c][1024 m] bf16 ; xt2[b][m][t*32+c] bf16 --------
__global__ __launch_bounds__(256) void k0_x(const float* __restrict__ x,
                     unsigned short* __restrict__ xbT, unsigned short* __restrict__ xt2){
  __shared__ unsigned short tile[64*770];        // pad 770: transpose reads conflict-free
  const int b  = blockIdx.x >> 4;
  const int m0 = (blockIdx.x & 15) << 6;
  const int tid = threadIdx.x;
  for (int i = tid; i < 64*192; i += 256){
    int mi = i / 192, c4 = (i - mi*192) << 2;
    f32x4 v = (f32x4){0.f,0.f,0.f,0.f};
    if (m0 + mi < NN) v = *(const f32x4*)(x + (size_t)(b*NN + m0 + mi)*768 + c4);
    unsigned short* tp = tile + mi*770 + c4;
    tp[0] = f2bf(v[0]); tp[1] = f2bf(v[1]); tp[2] = f2bf(v[2]); tp[3] = f2bf(v[3]);
  }
  __syncthreads();
  {
    const int seg = tid & 7, r0 = tid >> 3;
    for (int rr = 0; rr < 768; rr += 32){
      int r = rr + r0;
      int t = r >> 5, c = r & 31, ct = c*24 + t;
      u16x8 v;
      #pragma unroll
      for (int e = 0; e < 8; ++e) v[e] = tile[(seg*8 + e)*770 + ct];
      *(u16x8*)(xbT + ((size_t)b*TCN + r)*NP + m0 + seg*8) = v;
    }
  }
  if (m0 < NN){
    int rows = NN - m0; if (rows > 64) rows = 64;
    for (int i = tid; i < rows*96; i += 256){
      int mi = i / 96, s = i - mi*96;
      u16x8 v;
      #pragma unroll
      for (int e = 0; e < 8; ++e){
        int r = s*8 + e; int t = r >> 5, c = r & 31;
        v[e] = tile[mi*770 + c*24 + t];
      }
      *(u16x8*)(xt2 + (size_t)(b*NN + m0 + mi)*TCN + s*8) = v;
    }
  }
}

// ---------------- K0c: weights -> f-major bf16 ------------------------------------------
__global__ void k0_w(const float* __restrict__ Theta, const float* __restrict__ tw,
                     const float* __restrict__ rw,
                     unsigned short* __restrict__ ThT, unsigned short* __restrict__ WtT,
                     unsigned short* __restrict__ rwT){
  int i = blockIdx.x * 256 + threadIdx.x;
  if (i < 64*96){                       // ThT[f][kc] = Theta[k][c][f]
    int f = i / 96, kc = i - f*96;
    ThT[i] = f2bf(Theta[kc*64 + f]);
  }
  if (i < 64*192){                      // WtT[f][dt*64+fi] = tw[f][fi][0][dt]
    int f = i / 192, kk = i - f*192;
    int dt = kk >> 6, fi = kk & 63;
    WtT[i] = f2bf(tw[(f*64 + fi)*3 + dt]);
  }
  if (i < 64*32){                       // rwT[f][c] = rw[f][c][0][0]
    rwT[i] = f2bf(rw[i]);
  }
}

// ---------------- K1: fused cheb-GEMM (3k) + Theta-GEMM + relu -> spatial ----------------
// 256 threads / 4 waves (2 wr x 2 wc), block tile 64n x 128tc, BK=32, 32x32x16 MFMA,
// double-buffered LDS (40KB) + single barrier per K-step, both-sides XOR chunk swizzle.
__global__ __launch_bounds__(256, 3) void k1_cheb_theta(
    const unsigned short* __restrict__ cbT,
    const unsigned short* __restrict__ xbT,
    const unsigned short* __restrict__ ThT,
    unsigned short* __restrict__ spa)
{
  __shared__ __align__(16) unsigned short smem[20480];  // 40KB: 2 x (A[3][64][32] + B[128][32])

  int pB = blockIdx.x;
  int lb = (pB & 7) * 384 + (pB >> 3);     // bijective XCD-chunked swizzle (3072 = 8*384)
  const int tcb = lb % 6; lb /= 6;         // 6 consecutive blocks share the A-panel
  const int nt  = lb & 15;
  const int b   = lb >> 4;

  const int tid  = threadIdx.x;
  const int wid  = tid >> 6;
  const int lane = tid & 63;
  const int l31  = lane & 31;
  const int h    = lane >> 5;
  const int wr   = wid >> 1;    // n-half (32 rows)
  const int wc   = wid & 1;     // tc-half (64 cols)

  // staging: per 1KB gload a wave covers 16 rows x 4 chunks(16B); source chunk swizzled
  const int rl4 = lane >> 2;
  const int swz = (((lane & 3) ^ (rl4 & 3)) << 3);
  const unsigned short* baseA = cbT + (size_t)(nt*64 + rl4)*NP + swz;
  const unsigned short* baseB = xbT + ((size_t)b*TCN + tcb*128 + rl4)*NP + swz;
  char* smc = (char*)smem;

  // read-side swizzled chunk offsets (elements) for ks=0,1; logical chunk = ks*2 + h
  const int ch0 = ((h ^ (lane & 3)) << 3);
  const int ch1 = (((2 + h) ^ (lane & 3)) << 3);

  f32x16 acc[3][2];
  #pragma unroll
  for (int k = 0; k < 3; ++k)
    #pragma unroll
    for (int j = 0; j < 2; ++j)
      #pragma unroll
      for (int r = 0; r < 16; ++r) acc[k][j][r] = 0.f;

  const int rA  = wr*32 + l31;     // A-LDS row (n-local)
  const int rB0 = wc*64 + l31;     // B-LDS row (tc-local, j=0)

  // prologue
  {
    #pragma unroll
    for (int q = 0; q < 5; ++q){
      const int g = wid*5 + q;
      if (g < 12){
        const int k = g >> 2, rg = g & 3;
        GLOAD16(baseA + (size_t)k*NP*NP + rg*16*NP, smc + k*4096 + rg*1024);
      } else {
        const int rg = g - 12;
        GLOAD16(baseB + (size_t)rg*16*NP, smc + 12288 + rg*1024);
      }
    }
  }
  __syncthreads();

  int cur = 0;
  for (int step = 0; step < 32; ++step){
    if (step < 31){
      const int so = (step + 1) << 5;
      const int bo = (cur ^ 1) * 20480;
      #pragma unroll
      for (int q = 0; q < 5; ++q){
        const int g = wid*5 + q;
        if (g < 12){
          const int k = g >> 2, rg = g & 3;
          GLOAD16(baseA + (size_t)k*NP*NP + rg*16*NP + so, smc + bo + k*4096 + rg*1024);
        } else {
          const int rg = g - 12;
          GLOAD16(baseB + (size_t)rg*16*NP + so, smc + bo + 12288 + rg*1024);
        }
      }
    }
    const unsigned short* sb = smem + cur*10240;
    #pragma unroll
    for (int ks = 0; ks < 2; ++ks){
      const int ch = ks ? ch1 : ch0;
      s16x8 bf0 = *(const s16x8*)(sb + 6144 + rB0*32 + ch);
      s16x8 bf1 = *(const s16x8*)(sb + 6144 + (rB0 + 32)*32 + ch);
      #pragma unroll
      for (int k = 0; k < 3; ++k){
        s16x8 af = *(const s16x8*)(sb + k*2048 + rA*32 + ch);
        acc[k][0] = __builtin_amdgcn_mfma_f32_32x32x16_bf16(af, bf0, acc[k][0], 0, 0, 0);
        acc[k][1] = __builtin_amdgcn_mfma_f32_32x32x16_bf16(af, bf1, acc[k][1], 0, 0, 0);
      }
    }
    __syncthreads();
    cur ^= 1;
  }

  // ---- epilogue: 4 t-phases; y -> LDS bf16 (chunk-XOR) -> Theta MFMA (32x32) -> relu ----
  s16x8 b2[3][2];
  const int fE = wc*32 + l31;
  #pragma unroll
  for (int ch = 0; ch < 3; ++ch)
    #pragma unroll
    for (int ks = 0; ks < 2; ++ks)
      b2[ch][ks] = *(const s16x8*)(ThT + fE*96 + ch*32 + ks*16 + h*8);

  unsigned short* yl = smem;                 // [64 n][104 kc], chunk-XOR swizzled
  const int rowE = wr*32 + l31;
  #pragma unroll
  for (int p = 0; p < 4; ++p){
    __syncthreads();
    if (wc == (p >> 1)){
      const int jj = p & 1;
      #pragma unroll
      for (int k = 0; k < 3; ++k)
        #pragma unroll
        for (int r = 0; r < 16; ++r){
          const int nl = wr*32 + (r & 3) + ((r >> 2) << 3) + (h << 2);
          const int kc = k*32 + l31;
          const int q  = kc >> 3;
          yl[nl*104 + (((q ^ (nl & 3)) << 3) | (kc & 7))] = f2bf(acc[k][jj][r]);
        }
    }
    __syncthreads();
    f32x16 a2c;
    #pragma unroll
    for (int r = 0; r < 16; ++r) a2c[r] = 0.f;
    #pragma unroll
    for (int ch = 0; ch < 3; ++ch)
      #pragma unroll
      for (int ks = 0; ks < 2; ++ks){
        const int q = ch*4 + ks*2 + h;
        s16x8 a2 = *(const s16x8*)(yl + rowE*104 + ((q ^ (rowE & 3)) << 3));
        a2c = __builtin_amdgcn_mfma_f32_32x32x16_bf16(a2, b2[ch][ks], a2c, 0, 0, 0);
      }
    const int t = tcb*4 + p;
    #pragma unroll
    for (int r = 0; r < 16; ++r){
      const int nl = wr*32 + (r & 3) + ((r >> 2) << 3) + (h << 2);
      const int n  = nt*64 + nl;
      if (n < NN)
        spa[((size_t)(b*NN + n)*NT + t)*64 + fE] = f2bf(fmaxf(a2c[r], 0.f));
    }
  }
}

// ---------------- K2: time-conv (K=192) + residual (K=32) + gating -> out f32 -----------
__global__ __launch_bounds__(256, 3) void k2_out(
    const unsigned short* __restrict__ spa, const unsigned short* __restrict__ xt2,
    const unsigned short* __restrict__ WtT, const unsigned short* __restrict__ rwT,
    const float* __restrict__ tb, const float* __restrict__ rb,
    float* __restrict__ out)
{
  const int tid  = threadIdx.x;
  const int wid  = tid >> 6;
  const int lane = tid & 63;
  const int l16  = lane & 15;
  const int k8   = lane >> 4;
  const int gwave = blockIdx.x * 4 + wid;     // 0..11999

  s16x8 bw[6][4], br[4];
  #pragma unroll
  for (int ch = 0; ch < 6; ++ch)
    #pragma unroll
    for (int j = 0; j < 4; ++j)
      bw[ch][j] = *(const s16x8*)(WtT + (j*16 + l16)*192 + ch*32 + k8*8);
  #pragma unroll
  for (int j = 0; j < 4; ++j)
    br[j] = *(const s16x8*)(rwT + (j*16 + l16)*32 + k8*8);
  float tbv[4], rbv[4];
  #pragma unroll
  for (int j = 0; j < 4; ++j){ tbv[j] = tb[j*16 + l16]; rbv[j] = rb[j*16 + l16]; }

  for (int it = 0; it < 4; ++it){
    const int r0 = gwave*64 + it*16;          // base row, rows = (b*1000+n)*24+t
    const int rowA = r0 + l16;
    const int tA = rowA % 24;
    const int bn = rowA / 24;
    f32x4 acc_tc[4], acc_res[4];
    #pragma unroll
    for (int j = 0; j < 4; ++j){ acc_tc[j] = (f32x4){0.f,0.f,0.f,0.f}; acc_res[j] = (f32x4){0.f,0.f,0.f,0.f}; }

    #pragma unroll
    for (int ch = 0; ch < 6; ++ch){
      const int dt = ch >> 1, fh = (ch & 1) << 5;
      const int ts = tA + dt - 1;
      s16x8 a = (s16x8){0,0,0,0,0,0,0,0};
      if (ts >= 0 && ts < 24)
        a = *(const s16x8*)(spa + ((size_t)(bn*24 + ts) << 6) + fh + k8*8);
      #pragma unroll
      for (int j = 0; j < 4; ++j)
        acc_tc[j] = __builtin_amdgcn_mfma_f32_16x16x32_bf16(a, bw[ch][j], acc_tc[j], 0, 0, 0);
    }
    {
      s16x8 a = *(const s16x8*)(xt2 + (size_t)bn*768 + tA*32 + k8*8);
      #pragma unroll
      for (int j = 0; j < 4; ++j)
        acc_res[j] = __builtin_amdgcn_mfma_f32_16x16x32_bf16(a, br[j], acc_res[j], 0, 0, 0);
    }

    const int rowD = r0 + (k8 << 2);
    const int tD  = rowD % 24;                // multiple of 4, +3 never crosses 24
    const int bnD = rowD / 24;
    #pragma unroll
    for (int j = 0; j < 4; ++j){
      f32x4 v;
      #pragma unroll
      for (int r = 0; r < 4; ++r){
        float z = acc_tc[j][r] + tbv[j];
        float e = __expf(-z);                 // tanh(z)*sigmoid(z) = (1-e)/(1+e^2)
        float p = (1.f - e) * __builtin_amdgcn_rcpf(1.f + e*e);
        v[r] = acc_res[j][r] + rbv[j] + p;
      }
      *(f32x4*)(out + (((size_t)bnD << 6) + j*16 + l16)*24 + tD) = v;
    }
  }
}

// ---------------- launch -----------------------------------------------------------------
extern "C" void kernel_launch(void* const* d_in, const int* in_sizes, int n_in,
                              void* d_out, int out_size, void* d_ws, size_t ws_size,
                              hipStream_t stream) {
  const float* x     = (const float*)d_in[0];
  const float* cheb  = (const float*)d_in[1];
  const float* Theta = (const float*)d_in[2];
  const float* tw    = (const float*)d_in[3];
  const float* tb    = (const float*)d_in[4];
  const float* rw    = (const float*)d_in[5];
  const float* rb    = (const float*)d_in[6];
  float* out = (float*)d_out;

  char* ws = (char*)d_ws;
  size_t off = 0;
  auto alloc = [&](size_t bytes) -> void* {
    void* p = ws + off;
    off += (bytes + 255) & ~(size_t)255;
    return p;
  };
  unsigned short* cbT = (unsigned short*)alloc((size_t)3*NP*NP*2);        //  6.3 MB
  unsigned short* xbT = (unsigned short*)alloc((size_t)NB*TCN*NP*2);      // 50.3 MB
  unsigned short* xt2 = (unsigned short*)alloc((size_t)NB*NN*TCN*2);      // 49.2 MB
  unsigned short* spa = (unsigned short*)alloc((size_t)NB*NN*NT*64*2);    // 98.3 MB
  unsigned short* ThT = (unsigned short*)alloc((size_t)64*96*2);
  unsigned short* WtT = (unsigned short*)alloc((size_t)64*192*2);
  unsigned short* rwT = (unsigned short*)alloc((size_t)64*32*2);

  hipLaunchKernelGGL(k0_cheb, dim3(3072), dim3(256), 0, stream, cheb, cbT);
  hipLaunchKernelGGL(k0_x,    dim3(512),  dim3(256), 0, stream, x, xbT, xt2);
  hipLaunchKernelGGL(k0_w,    dim3(48),   dim3(256), 0, stream, Theta, tw, rw, ThT, WtT, rwT);
  hipLaunchKernelGGL(k1_cheb_theta, dim3(32*16*6), dim3(256), 0, stream, cbT, xbT, ThT, spa);
  hipLaunchKernelGGL(k2_out,  dim3(3000), dim3(256), 0, stream, spa, xt2, WtT, rwT, tb, rb, out);
}

// Round 5
// 438.024 us; speedup vs baseline: 1.0446x; 1.0127x over previous
//
#include <hip/hip_runtime.h>
#include <math.h>

typedef __attribute__((ext_vector_type(4))) float f32x4;
typedef __attribute__((ext_vector_type(16))) float f32x16;
typedef __attribute__((ext_vector_type(8))) short s16x8;
typedef __attribute__((ext_vector_type(8))) unsigned short u16x8;
typedef __attribute__((ext_vector_type(4))) unsigned short u16x4;

#define NB 32
#define NN 1000
#define NT 24
#define NP 1024
#define TCN 768

#define GLOAD16(g, l) __builtin_amdgcn_global_load_lds( \
    (const __attribute__((address_space(1))) unsigned int*)(g), \
    (__attribute__((address_space(3))) unsigned int*)(l), 16, 0, 0)

__device__ __forceinline__ unsigned short f2bf(float f){
  union { float fv; unsigned int u; } v; v.fv = f;
  unsigned int r = v.u + 0x7FFFu + ((v.u >> 16) & 1u);
  return (unsigned short)(r >> 16);
}

// ---------------- K0a: cheb[3][1000][1000] f32 -> cbT[3][1024][1024] bf16 (zero pad) ----
__global__ void k0_cheb(const float* __restrict__ cheb, unsigned short* __restrict__ cbT){
  int idx = blockIdx.x * 256 + threadIdx.x;      // 3*1024*1024/4 threads
  int base = idx << 2;
  int m = base & (NP - 1);
  int r = base >> 10;
  int n = r & (NP - 1);
  int k = r >> 10;
  u16x4 o;
  #pragma unroll
  for (int i = 0; i < 4; ++i){
    int mm = m + i;
    float v = (n < NN && mm < NN) ? cheb[((long)k*NN + n)*NN + mm] : 0.f;
    o[i] = f2bf(v);
  }
  *(u16x4*)(cbT + base) = o;
}

// ---------------- K0b: x -> xbT[b][t*32+c][1024 m] bf16 ; xt2[b][m][t*32+c] bf16 --------
__global__ __launch_bounds__(256) void k0_x(const float* __restrict__ x,
                     unsigned short* __restrict__ xbT, unsigned short* __restrict__ xt2){
  __shared__ unsigned short tile[64*770];        // pad 770: transpose reads conflict-free
  const int b  = blockIdx.x >> 4;
  const int m0 = (blockIdx.x & 15) << 6;
  const int tid = threadIdx.x;
  for (int i = tid; i < 64*192; i += 256){
    int mi = i / 192, c4 = (i - mi*192) << 2;
    f32x4 v = (f32x4){0.f,0.f,0.f,0.f};
    if (m0 + mi < NN) v = *(const f32x4*)(x + (size_t)(b*NN + m0 + mi)*768 + c4);
    unsigned short* tp = tile + mi*770 + c4;
    tp[0] = f2bf(v[0]); tp[1] = f2bf(v[1]); tp[2] = f2bf(v[2]); tp[3] = f2bf(v[3]);
  }
  __syncthreads();
  {
    const int seg = tid & 7, r0 = tid >> 3;
    for (int rr = 0; rr < 768; rr += 32){
      int r = rr + r0;
      int t = r >> 5, c = r & 31, ct = c*24 + t;
      u16x8 v;
      #pragma unroll
      for (int e = 0; e < 8; ++e) v[e] = tile[(seg*8 + e)*770 + ct];
      *(u16x8*)(xbT + ((size_t)b*TCN + r)*NP + m0 + seg*8) = v;
    }
  }
  if (m0 < NN){
    int rows = NN - m0; if (rows > 64) rows = 64;
    for (int i = tid; i < rows*96; i += 256){
      int mi = i / 96, s = i - mi*96;
      u16x8 v;
      #pragma unroll
      for (int e = 0; e < 8; ++e){
        int r = s*8 + e; int t = r >> 5, c = r & 31;
        v[e] = tile[mi*770 + c*24 + t];
      }
      *(u16x8*)(xt2 + (size_t)(b*NN + m0 + mi)*TCN + s*8) = v;
    }
  }
}

// ---------------- K0c: weights -> f-major bf16 ------------------------------------------
__global__ void k0_w(const float* __restrict__ Theta, const float* __restrict__ tw,
                     const float* __restrict__ rw,
                     unsigned short* __restrict__ ThT, unsigned short* __restrict__ WtT,
                     unsigned short* __restrict__ rwT){
  int i = blockIdx.x * 256 + threadIdx.x;
  if (i < 64*96){                       // ThT[f][kc] = Theta[k][c][f]
    int f = i / 96, kc = i - f*96;
    ThT[i] = f2bf(Theta[kc*64 + f]);
  }
  if (i < 64*192){                      // WtT[f][dt*64+fi] = tw[f][fi][0][dt]
    int f = i / 192, kk = i - f*192;
    int dt = kk >> 6, fi = kk & 63;
    WtT[i] = f2bf(tw[(f*64 + fi)*3 + dt]);
  }
  if (i < 64*32){                       // rwT[f][c] = rw[f][c][0][0]
    rwT[i] = f2bf(rw[i]);
  }
}

// ---------------- K1: fused cheb-GEMM (3k) + Theta-GEMM + relu -> spatial ----------------
// 256 threads / 4 waves (2 wr x 2 wc), block tile 64n x 128tc, BK=32, 32x32x16 MFMA,
// double-buffered LDS (40KB) + single barrier per K-step.
// Swizzle s(row) = (row>>1)&3 on BOTH sides: bank-group = (row&1)*4 + q^s covers all 8
// groups per 8 lanes -> conflict-free ds_read_b128 (R4 bug was s(row)=row&3, 8-way).
__global__ __launch_bounds__(256, 3) void k1_cheb_theta(
    const unsigned short* __restrict__ cbT,
    const unsigned short* __restrict__ xbT,
    const unsigned short* __restrict__ ThT,
    unsigned short* __restrict__ spa)
{
  __shared__ __align__(16) unsigned short smem[20480];  // 40KB: 2 x (A[3][64][32] + B[128][32])

  int pB = blockIdx.x;
  int lb = (pB & 7) * 384 + (pB >> 3);     // bijective XCD-chunked swizzle (3072 = 8*384)
  const int tcb = lb % 6; lb /= 6;         // 6 consecutive blocks share the A-panel
  const int nt  = lb & 15;
  const int b   = lb >> 4;

  const int tid  = threadIdx.x;
  const int wid  = tid >> 6;
  const int lane = tid & 63;
  const int l31  = lane & 31;
  const int h    = lane >> 5;
  const int wr   = wid >> 1;    // n-half (32 rows)
  const int wc   = wid & 1;     // tc-half (64 cols)

  // staging: per 1KB gload a wave covers 16 rows x 4 chunks(16B); source chunk swizzled
  const int rl4 = lane >> 2;
  const int swz = (((lane & 3) ^ ((rl4 >> 1) & 3)) << 3);
  const unsigned short* baseA = cbT + (size_t)(nt*64 + rl4)*NP + swz;
  const unsigned short* baseB = xbT + ((size_t)b*TCN + tcb*128 + rl4)*NP + swz;
  char* smc = (char*)smem;

  // read-side swizzled chunk offsets (elements); s(row) = (row>>1)&3 = (l31>>1)&3
  const int s_rd = (l31 >> 1) & 3;
  const int ch0 = ((h ^ s_rd) << 3);
  const int ch1 = (((2 + h) ^ s_rd) << 3);

  f32x16 acc[3][2];
  #pragma unroll
  for (int k = 0; k < 3; ++k)
    #pragma unroll
    for (int j = 0; j < 2; ++j)
      #pragma unroll
      for (int r = 0; r < 16; ++r) acc[k][j][r] = 0.f;

  const int rA  = wr*32 + l31;     // A-LDS row (n-local)
  const int rB0 = wc*64 + l31;     // B-LDS row (tc-local, j=0)

  // prologue
  {
    #pragma unroll
    for (int q = 0; q < 5; ++q){
      const int g = wid*5 + q;
      if (g < 12){
        const int k = g >> 2, rg = g & 3;
        GLOAD16(baseA + (size_t)k*NP*NP + rg*16*NP, smc + k*4096 + rg*1024);
      } else {
        const int rg = g - 12;
        GLOAD16(baseB + (size_t)rg*16*NP, smc + 12288 + rg*1024);
      }
    }
  }
  __syncthreads();

  int cur = 0;
  for (int step = 0; step < 32; ++step){
    if (step < 31){
      const int so = (step + 1) << 5;
      const int bo = (cur ^ 1) * 20480;
      #pragma unroll
      for (int q = 0; q < 5; ++q){
        const int g = wid*5 + q;
        if (g < 12){
          const int k = g >> 2, rg = g & 3;
          GLOAD16(baseA + (size_t)k*NP*NP + rg*16*NP + so, smc + bo + k*4096 + rg*1024);
        } else {
          const int rg = g - 12;
          GLOAD16(baseB + (size_t)rg*16*NP + so, smc + bo + 12288 + rg*1024);
        }
      }
    }
    const unsigned short* sb = smem + cur*10240;
    #pragma unroll
    for (int ks = 0; ks < 2; ++ks){
      const int ch = ks ? ch1 : ch0;
      s16x8 bf0 = *(const s16x8*)(sb + 6144 + rB0*32 + ch);
      s16x8 bf1 = *(const s16x8*)(sb + 6144 + (rB0 + 32)*32 + ch);
      #pragma unroll
      for (int k = 0; k < 3; ++k){
        s16x8 af = *(const s16x8*)(sb + k*2048 + rA*32 + ch);
        acc[k][0] = __builtin_amdgcn_mfma_f32_32x32x16_bf16(af, bf0, acc[k][0], 0, 0, 0);
        acc[k][1] = __builtin_amdgcn_mfma_f32_32x32x16_bf16(af, bf1, acc[k][1], 0, 0, 0);
      }
    }
    __syncthreads();
    cur ^= 1;
  }

  // ---- epilogue: 4 t-phases; y -> LDS bf16 (chunk-XOR) -> Theta MFMA (32x32) -> relu ----
  s16x8 b2[3][2];
  const int fE = wc*32 + l31;
  #pragma unroll
  for (int ch = 0; ch < 3; ++ch)
    #pragma unroll
    for (int ks = 0; ks < 2; ++ks)
      b2[ch][ks] = *(const s16x8*)(ThT + fE*96 + ch*32 + ks*16 + h*8);

  unsigned short* yl = smem;                 // [64 n][104 kc], chunk-XOR swizzled
  const int rowE = wr*32 + l31;
  #pragma unroll
  for (int p = 0; p < 4; ++p){
    __syncthreads();
    if (wc == (p >> 1)){
      const int jj = p & 1;
      #pragma unroll
      for (int k = 0; k < 3; ++k)
        #pragma unroll
        for (int r = 0; r < 16; ++r){
          const int nl = wr*32 + (r & 3) + ((r >> 2) << 3) + (h << 2);
          const int kc = k*32 + l31;
          const int q  = kc >> 3;
          yl[nl*104 + (((q ^ (nl & 3)) << 3) | (kc & 7))] = f2bf(acc[k][jj][r]);
        }
    }
    __syncthreads();
    f32x16 a2c;
    #pragma unroll
    for (int r = 0; r < 16; ++r) a2c[r] = 0.f;
    #pragma unroll
    for (int ch = 0; ch < 3; ++ch)
      #pragma unroll
      for (int ks = 0; ks < 2; ++ks){
        const int q = ch*4 + ks*2 + h;
        s16x8 a2 = *(const s16x8*)(yl + rowE*104 + ((q ^ (rowE & 3)) << 3));
        a2c = __builtin_amdgcn_mfma_f32_32x32x16_bf16(a2, b2[ch][ks], a2c, 0, 0, 0);
      }
    const int t = tcb*4 + p;
    #pragma unroll
    for (int r = 0; r < 16; ++r){
      const int nl = wr*32 + (r & 3) + ((r >> 2) << 3) + (h << 2);
      const int n  = nt*64 + nl;
      if (n < NN)
        spa[((size_t)(b*NN + n)*NT + t)*64 + fE] = f2bf(fmaxf(a2c[r], 0.f));
    }
  }
}

// ---------------- K2: time-conv (K=192) + residual (K=32) + gating -> out f32 -----------
__global__ __launch_bounds__(256, 3) void k2_out(
    const unsigned short* __restrict__ spa, const unsigned short* __restrict__ xt2,
    const unsigned short* __restrict__ WtT, const unsigned short* __restrict__ rwT,
    const float* __restrict__ tb, const float* __restrict__ rb,
    float* __restrict__ out)
{
  const int tid  = threadIdx.x;
  const int wid  = tid >> 6;
  const int lane = tid & 63;
  const int l16  = lane & 15;
  const int k8   = lane >> 4;
  const int gwave = blockIdx.x * 4 + wid;     // 0..11999

  s16x8 bw[6][4], br[4];
  #pragma unroll
  for (int ch = 0; ch < 6; ++ch)
    #pragma unroll
    for (int j = 0; j < 4; ++j)
      bw[ch][j] = *(const s16x8*)(WtT + (j*16 + l16)*192 + ch*32 + k8*8);
  #pragma unroll
  for (int j = 0; j < 4; ++j)
    br[j] = *(const s16x8*)(rwT + (j*16 + l16)*32 + k8*8);
  float tbv[4], rbv[4];
  #pragma unroll
  for (int j = 0; j < 4; ++j){ tbv[j] = tb[j*16 + l16]; rbv[j] = rb[j*16 + l16]; }

  for (int it = 0; it < 4; ++it){
    const int r0 = gwave*64 + it*16;          // base row, rows = (b*1000+n)*24+t
    const int rowA = r0 + l16;
    const int tA = rowA % 24;
    const int bn = rowA / 24;
    f32x4 acc_tc[4], acc_res[4];
    #pragma unroll
    for (int j = 0; j < 4; ++j){ acc_tc[j] = (f32x4){0.f,0.f,0.f,0.f}; acc_res[j] = (f32x4){0.f,0.f,0.f,0.f}; }

    #pragma unroll
    for (int ch = 0; ch < 6; ++ch){
      const int dt = ch >> 1, fh = (ch & 1) << 5;
      const int ts = tA + dt - 1;
      s16x8 a = (s16x8){0,0,0,0,0,0,0,0};
      if (ts >= 0 && ts < 24)
        a = *(const s16x8*)(spa + ((size_t)(bn*24 + ts) << 6) + fh + k8*8);
      #pragma unroll
      for (int j = 0; j < 4; ++j)
        acc_tc[j] = __builtin_amdgcn_mfma_f32_16x16x32_bf16(a, bw[ch][j], acc_tc[j], 0, 0, 0);
    }
    {
      s16x8 a = *(const s16x8*)(xt2 + (size_t)bn*768 + tA*32 + k8*8);
      #pragma unroll
      for (int j = 0; j < 4; ++j)
        acc_res[j] = __builtin_amdgcn_mfma_f32_16x16x32_bf16(a, br[j], acc_res[j], 0, 0, 0);
    }

    const int rowD = r0 + (k8 << 2);
    const int tD  = rowD % 24;                // multiple of 4, +3 never crosses 24
    const int bnD = rowD / 24;
    #pragma unroll
    for (int j = 0; j < 4; ++j){
      f32x4 v;
      #pragma unroll
      for (int r = 0; r < 4; ++r){
        float z = acc_tc[j][r] + tbv[j];
        float e = __expf(-z);                 // tanh(z)*sigmoid(z) = (1-e)/(1+e^2)
        float p = (1.f - e) * __builtin_amdgcn_rcpf(1.f + e*e);
        v[r] = acc_res[j][r] + rbv[j] + p;
      }
      *(f32x4*)(out + (((size_t)bnD << 6) + j*16 + l16)*24 + tD) = v;
    }
  }
}

// ---------------- launch -----------------------------------------------------------------
extern "C" void kernel_launch(void* const* d_in, const int* in_sizes, int n_in,
                              void* d_out, int out_size, void* d_ws, size_t ws_size,
                              hipStream_t stream) {
  const float* x     = (const float*)d_in[0];
  const float* cheb  = (const float*)d_in[1];
  const float* Theta = (const float*)d_in[2];
  const float* tw    = (const float*)d_in[3];
  const float* tb    = (const float*)d_in[4];
  const float* rw    = (const float*)d_in[5];
  const float* rb    = (const float*)d_in[6];
  float* out = (float*)d_out;

  char* ws = (char*)d_ws;
  size_t off = 0;
  auto alloc = [&](size_t bytes) -> void* {
    void* p = ws + off;
    off += (bytes + 255) & ~(size_t)255;
    return p;
  };
  unsigned short* cbT = (unsigned short*)alloc((size_t)3*NP*NP*2);        //  6.3 MB
  unsigned short* xbT = (unsigned short*)alloc((size_t)NB*TCN*NP*2);      // 50.3 MB
  unsigned short* xt2 = (unsigned short*)alloc((size_t)NB*NN*TCN*2);      // 49.2 MB
  unsigned short* spa = (unsigned short*)alloc((size_t)NB*NN*NT*64*2);    // 98.3 MB
  unsigned short* ThT = (unsigned short*)alloc((size_t)64*96*2);
  unsigned short* WtT = (unsigned short*)alloc((size_t)64*192*2);
  unsigned short* rwT = (unsigned short*)alloc((size_t)64*32*2);

  hipLaunchKernelGGL(k0_cheb, dim3(3072), dim3(256), 0, stream, cheb, cbT);
  hipLaunchKernelGGL(k0_x,    dim3(512),  dim3(256), 0, stream, x, xbT, xt2);
  hipLaunchKernelGGL(k0_w,    dim3(48),   dim3(256), 0, stream, Theta, tw, rw, ThT, WtT, rwT);
  hipLaunchKernelGGL(k1_cheb_theta, dim3(32*16*6), dim3(256), 0, stream, cbT, xbT, ThT, spa);
  hipLaunchKernelGGL(k2_out,  dim3(3000), dim3(256), 0, stream, spa, xt2, WtT, rwT, tb, rb, out);
}